// Round 19
// baseline (325.219 us; speedup 1.0000x reference)
//
#include <hip/hip_runtime.h>
#include <hip/hip_bf16.h>

#define B_ 2
#define S_ 2048
#define HID_ 2048
#define H_ 16
#define KVH_ 8
#define D_ 128
#define G_ 2
#define EPS_ 1e-6f
#define SCALE_ 0.08838834764831845f
// SCALE * log2(e): scores computed directly in log2 domain (folded into Q)
#define SCALE2_ 0.1275313760443445f
#define NQKV 6144

typedef __hip_bfloat16 bf16;
typedef __attribute__((ext_vector_type(8))) short s8v;   // 8 bf16 = 4 VGPR
typedef __attribute__((ext_vector_type(4))) float f4v;   // MFMA C/D

__device__ __forceinline__ unsigned short f2b(float f) {
    __hip_bfloat16 h = __float2bfloat16(f);
    return *reinterpret_cast<unsigned short*>(&h);
}
__device__ __forceinline__ float b2f(short u) {
    unsigned int x = ((unsigned int)(unsigned short)u) << 16;
    return __builtin_bit_cast(float, x);
}

__device__ __forceinline__ f4v MFMA(s8v a, s8v b, f4v c) {
    return __builtin_amdgcn_mfma_f32_16x16x32_bf16(a, b, c, 0, 0, 0);
}

__device__ __forceinline__ void gl_lds16(const void* g, void* l) {
    __builtin_amdgcn_global_load_lds(
        (const __attribute__((address_space(1))) void*)g,
        (__attribute__((address_space(3))) void*)l, 16, 0, 0);
}

__device__ __forceinline__ void cstore(float* p, float v) { *p = v; }
__device__ __forceinline__ void cstore(short* p, float v) { *p = (short)f2b(v); }

// ---- DPP 16-lane butterfly reduction (VALU, no LDS swizzle) ----
template <int CTRL>
__device__ __forceinline__ float dpp_f(float x) {
    return __builtin_bit_cast(float,
        __builtin_amdgcn_update_dpp(0, __builtin_bit_cast(int, x), CTRL, 0xF, 0xF, true));
}
__device__ __forceinline__ float red16_max(float v) {
    v = fmaxf(v, dpp_f<0xB1>(v));
    v = fmaxf(v, dpp_f<0x4E>(v));
    v = fmaxf(v, dpp_f<0x124>(v));
    v = fmaxf(v, dpp_f<0x128>(v));
    return v;
}
__device__ __forceinline__ float red16_sum(float v) {
    v += dpp_f<0xB1>(v);
    v += dpp_f<0x4E>(v);
    v += dpp_f<0x124>(v);
    v += dpp_f<0x128>(v);
    return v;
}

// ---------------------------------------------------------------------------
// fp32 -> bf16 bulk convert (vectorized)
// ---------------------------------------------------------------------------
__global__ __launch_bounds__(256) void f2bf_kernel(const float* __restrict__ in,
                                                   short* __restrict__ out, int n4) {
    int i = blockIdx.x * 256 + threadIdx.x;
    if (i >= n4) return;
    const float4 v = *(const float4*)(in + (size_t)i * 4);
    ushort4 o;
    o.x = f2b(v.x); o.y = f2b(v.y); o.z = f2b(v.z); o.w = f2b(v.w);
    *(ushort4*)(out + (size_t)i * 4) = o;
}

// ---------------------------------------------------------------------------
// Merged QKV weight transpose: [Wq|Wk|Wv] (K x {4096|1024|1024} fp32)
// -> Wt[6144][2048] bf16.  One launch.
// ---------------------------------------------------------------------------
__global__ __launch_bounds__(256) void qkvw_transpose(const float* __restrict__ Wq,
                                                      const float* __restrict__ Wk,
                                                      const float* __restrict__ Wv,
                                                      short* __restrict__ out) {
    __shared__ short t[32][33];
    const int n0 = blockIdx.x * 32, k0 = blockIdx.y * 32;
    const float* src;
    int scol, sN;
    if (n0 < 4096)      { src = Wq; scol = n0;        sN = 4096; }
    else if (n0 < 5120) { src = Wk; scol = n0 - 4096; sN = 1024; }
    else                { src = Wv; scol = n0 - 5120; sN = 1024; }
    const int tx = threadIdx.x, ty = threadIdx.y;
#pragma unroll
    for (int j = 0; j < 4; j++) {
        const int r = ty + j * 8;
        t[r][tx] = (short)f2b(src[(size_t)(k0 + r) * sN + scol + tx]);
    }
    __syncthreads();
#pragma unroll
    for (int j = 0; j < 4; j++) {
        const int r = ty + j * 8;
        out[(size_t)(n0 + r) * HID_ + k0 + tx] = t[tx][r];
    }
}

// ---------------------------------------------------------------------------
// W[K][N] fp32 -> Wt[N][K] bf16 (for Wo)
// ---------------------------------------------------------------------------
__global__ __launch_bounds__(256) void transpose_conv(const float* __restrict__ in,
                                                      short* __restrict__ out,
                                                      int K, int N) {
    __shared__ short t[32][33];
    const int n0 = blockIdx.x * 32, k0 = blockIdx.y * 32;
    const int tx = threadIdx.x, ty = threadIdx.y;
#pragma unroll
    for (int j = 0; j < 4; j++) {
        const int r = ty + j * 8;
        t[r][tx] = (short)f2b(in[(size_t)(k0 + r) * N + n0 + tx]);
    }
    __syncthreads();
#pragma unroll
    for (int j = 0; j < 4; j++) {
        const int r = ty + j * 8;
        out[(size_t)(n0 + r) * K + k0 + tx] = t[tx][r];
    }
}

// ---------------------------------------------------------------------------
// V transpose per head: qkv v-columns -> vt[(b*KVH+kvh)][D][S]
// ---------------------------------------------------------------------------
__global__ __launch_bounds__(256) void transpose_v(const short* __restrict__ in,
                                                   short* __restrict__ out) {
    __shared__ short t[32][33];
    const int s0 = blockIdx.x * 32, d0 = blockIdx.y * 32, bk = blockIdx.z;
    const int b = bk / KVH_, kvh = bk % KVH_;
    const short* ip = in + (size_t)b * S_ * NQKV + kvh * D_;
    const int tx = threadIdx.x, ty = threadIdx.y;
#pragma unroll
    for (int j = 0; j < 4; j++) {
        const int r = ty + j * 8;
        t[r][tx] = ip[(size_t)(s0 + r) * NQKV + d0 + tx];
    }
    __syncthreads();
#pragma unroll
    for (int j = 0; j < 4; j++) {
        const int r = ty + j * 8;
        out[((size_t)bk * D_ + d0 + r) * S_ + s0 + tx] = t[tx][r];
    }
}

// ---------------------------------------------------------------------------
// 256x384 deep-pipelined MFMA GEMM (B^T form). Same frozen 3-buffer
// counted-vmcnt schedule as the proven 256^2 kernel, but N-tile widened to
// 384 so grid = (16,16) = 256 blocks = EXACTLY one round of 256 CUs
// (the 256^2 version ran 384 blocks at 1 block/CU = 1.5 rounds, idling
// half the machine in round 2). Per-thread ledger: 5 loads/tile
// (A:2 phase0, B:3 phase1) -> gate vmcnt(5). LDS 48+72 = 120 KB.
// 8 waves (2M x 4N), per-wave 128x96 (acc[8][6]).
// ---------------------------------------------------------------------------
__global__ __launch_bounds__(512, 1) void gemm256(const short* __restrict__ A,
                                                  const short* __restrict__ Bt,
                                                  short* __restrict__ C,
                                                  int M, int N, int K) {
    __shared__ __align__(16) short As[3][256][32];   // 48 KB
    __shared__ __align__(16) short Bs[3][384][32];   // 72 KB
    const int tid = threadIdx.x;
    const int w = tid >> 6, l = tid & 63;
    const int lr = l & 15, g = l >> 4;
    const int nwg = gridDim.x * gridDim.y;
    int bid = blockIdx.y * gridDim.x + blockIdx.x;
    bid = (bid & 7) * (nwg >> 3) + (bid >> 3);       // XCD swizzle (nwg%8==0)
    const int bx = bid % gridDim.x, by = bid / gridDim.x;
    const int row0 = by * 256, col0 = bx * 384;
    const int wr = w >> 2, wc = w & 3;               // 2M x 4N wave grid

    f4v acc[8][6];
#pragma unroll
    for (int i = 0; i < 8; i++)
#pragma unroll
        for (int j = 0; j < 6; j++) acc[i][j] = (f4v)0.f;

    const int srow = l >> 2;
    const int schunk = (l & 3) ^ ((l >> 3) & 3);     // pre-swizzled source chunk
    const int rdslot = (g ^ ((lr >> 1) & 3)) * 8;    // swizzled read slot (elems)

    auto stageA = [&](int buf, int t) {
        const int kt = t * 32;
#pragma unroll
        for (int i = 0; i < 2; i++) {
            const int rb = w * 32 + i * 16;
            gl_lds16(A + (size_t)(row0 + rb + srow) * K + kt + schunk * 8,
                     &As[buf][rb][0]);
        }
    };
    auto stageB = [&](int buf, int t) {
        const int kt = t * 32;
#pragma unroll
        for (int i = 0; i < 3; i++) {
            const int rb = w * 48 + i * 16;
            gl_lds16(Bt + (size_t)(col0 + rb + srow) * K + kt + schunk * 8,
                     &Bs[buf][rb][0]);
        }
    };

    const int nt = K >> 5;                           // 64 tiles at K=2048
    stageA(0, 0); stageB(0, 0);
    stageA(1, 1); stageB(1, 1);

#pragma unroll 1
    for (int t = 0; t < nt; t++) {
        const int buf = t % 3;
        const int nbuf = (t + 2) % 3;

        __builtin_amdgcn_sched_barrier(0);
        if (t + 1 < nt) {
            asm volatile("s_waitcnt vmcnt(5)" ::: "memory");
        } else {
            asm volatile("s_waitcnt vmcnt(0)" ::: "memory");
        }
        __builtin_amdgcn_sched_barrier(0);
        __builtin_amdgcn_s_barrier();
        __builtin_amdgcn_sched_barrier(0);

        // phase 0: B frags + A rows 0-63, stage A of t+2, MFMA
        s8v b[6], a[4];
#pragma unroll
        for (int ni = 0; ni < 6; ni++)
            b[ni] = *(const s8v*)&Bs[buf][wc * 96 + ni * 16 + lr][rdslot];
#pragma unroll
        for (int mi = 0; mi < 4; mi++)
            a[mi] = *(const s8v*)&As[buf][wr * 128 + mi * 16 + lr][rdslot];
        if (t + 2 < nt) stageA(nbuf, t + 2);
        __builtin_amdgcn_s_setprio(1);
#pragma unroll
        for (int mi = 0; mi < 4; mi++)
#pragma unroll
            for (int ni = 0; ni < 6; ni++)
                acc[mi][ni] = MFMA(a[mi], b[ni], acc[mi][ni]);
        __builtin_amdgcn_s_setprio(0);
        __builtin_amdgcn_s_barrier();
        __builtin_amdgcn_sched_barrier(0);

        // phase 1: A rows 64-127, stage B of t+2, MFMA
        s8v a2[4];
#pragma unroll
        for (int mi = 0; mi < 4; mi++)
            a2[mi] = *(const s8v*)&As[buf][wr * 128 + (4 + mi) * 16 + lr][rdslot];
        if (t + 2 < nt) stageB(nbuf, t + 2);
        __builtin_amdgcn_s_setprio(1);
#pragma unroll
        for (int mi = 0; mi < 4; mi++)
#pragma unroll
            for (int ni = 0; ni < 6; ni++)
                acc[4 + mi][ni] = MFMA(a2[mi], b[ni], acc[4 + mi][ni]);
        __builtin_amdgcn_s_setprio(0);
    }

#pragma unroll
    for (int mi = 0; mi < 8; mi++)
#pragma unroll
        for (int ni = 0; ni < 6; ni++) {
            const int row = row0 + wr * 128 + mi * 16 + g * 4;
            const int col = col0 + wc * 96 + ni * 16 + lr;
#pragma unroll
            for (int j = 0; j < 4; j++)
                cstore(&C[(size_t)(row + j) * N + col], acc[mi][ni][j]);
        }
}

// ---------------------------------------------------------------------------
// Wo GEMM: 256x128 tile, 3-buffer counted-vmcnt pipeline, grid (16,16)=256
// blocks = exactly 1/CU. 8 waves (4M x 2N), per-wave 64x64 (4x4 frags).
// A read from qkv gated layout: (row,k) at row*NQKV + ((k>>7)<<8) + (k&127).
// ---------------------------------------------------------------------------
__global__ __launch_bounds__(512, 1) void gemm_wo(const short* __restrict__ A,
                                                  const short* __restrict__ Bt,
                                                  float* __restrict__ C,
                                                  int M, int N, int K) {
    __shared__ __align__(16) short As[3][256][32];   // 48 KB
    __shared__ __align__(16) short Bs[3][128][32];   // 24 KB
    const int tid = threadIdx.x;
    const int w = tid >> 6, l = tid & 63;
    const int lr = l & 15, g = l >> 4;
    const int nwg = gridDim.x * gridDim.y;
    int bid = blockIdx.y * gridDim.x + blockIdx.x;
    bid = (bid & 7) * (nwg >> 3) + (bid >> 3);       // XCD swizzle (nwg%8==0)
    const int bx = bid % gridDim.x, by = bid / gridDim.x;
    const int row0 = by * 256, col0 = bx * 128;
    const int wr = w >> 1, wc = w & 1;               // 4M x 2N wave grid

    f4v acc[4][4];
#pragma unroll
    for (int i = 0; i < 4; i++)
#pragma unroll
        for (int j = 0; j < 4; j++) acc[i][j] = (f4v)0.f;

    const int srow = l >> 2;
    const int schunk = (l & 3) ^ ((l >> 3) & 3);
    const int rdslot = (g ^ ((lr >> 1) & 3)) * 8;

    auto stage = [&](int buf, int t) {
        const int k = t * 32 + schunk * 8;
        const size_t goff = ((size_t)((k >> 7) << 8)) + (k & 127);
#pragma unroll
        for (int i = 0; i < 2; i++) {
            const int rb = w * 32 + i * 16;
            gl_lds16(A + (size_t)(row0 + rb + srow) * NQKV + goff, &As[buf][rb][0]);
        }
        gl_lds16(Bt + (size_t)(col0 + w * 16 + srow) * K + k, &Bs[buf][w * 16][0]);
    };

    const int nt = K >> 5;                           // 64
    stage(0, 0);
    stage(1, 1);

#pragma unroll 1
    for (int t = 0; t < nt; t++) {
        const int buf = t % 3;
        __builtin_amdgcn_sched_barrier(0);
        if (t + 1 < nt) {
            asm volatile("s_waitcnt vmcnt(3)" ::: "memory");
        } else {
            asm volatile("s_waitcnt vmcnt(0)" ::: "memory");
        }
        __builtin_amdgcn_sched_barrier(0);
        __builtin_amdgcn_s_barrier();
        __builtin_amdgcn_sched_barrier(0);

        s8v a[4], b[4];
#pragma unroll
        for (int mi = 0; mi < 4; mi++)
            a[mi] = *(const s8v*)&As[buf][wr * 64 + mi * 16 + lr][rdslot];
#pragma unroll
        for (int ni = 0; ni < 4; ni++)
            b[ni] = *(const s8v*)&Bs[buf][wc * 64 + ni * 16 + lr][rdslot];

        if (t + 2 < nt) stage((t + 2) % 3, t + 2);

        __builtin_amdgcn_s_setprio(1);
#pragma unroll
        for (int mi = 0; mi < 4; mi++)
#pragma unroll
            for (int ni = 0; ni < 4; ni++)
                acc[mi][ni] = MFMA(a[mi], b[ni], acc[mi][ni]);
        __builtin_amdgcn_s_setprio(0);
    }

#pragma unroll
    for (int mi = 0; mi < 4; mi++)
#pragma unroll
        for (int ni = 0; ni < 4; ni++) {
            const int row = row0 + wr * 64 + mi * 16 + g * 4;
            const int col = col0 + wc * 64 + ni * 16 + lr;
#pragma unroll
            for (int j = 0; j < 4; j++)
                cstore(&C[(size_t)(row + j) * N + col], acc[mi][ni][j]);
        }
}

// ---------------------------------------------------------------------------
// Fused RMSNorm + RoPE, one block per (b,s): cos/sin/norm-weights loaded
// ONCE, then loop the 24 heads (16 Q + 8 K).
// ---------------------------------------------------------------------------
__global__ __launch_bounds__(128) void norm_rope(const bf16* __restrict__ qkv,
                                                 const float* __restrict__ qnw,
                                                 const float* __restrict__ knw,
                                                 const float* __restrict__ cosb,
                                                 const float* __restrict__ sinb,
                                                 bf16* __restrict__ qro,
                                                 bf16* __restrict__ kro) {
    const int bs = blockIdx.x;                   // 0..B*S-1
    const int s = bs % S_;
    const int b = bs / S_;
    const int d = threadIdx.x;

    __shared__ float red[2];
    __shared__ float sh[128];

    const size_t cs_i = ((size_t)b * S_ + s) * D_ + d;
    const float cv = cosb[cs_i], sv = sinb[cs_i];
    const float qw = qnw[d], kw = knw[d];
    const size_t rowbase = (size_t)(b * S_ + s) * NQKV;

#pragma unroll 1
    for (int ht = 0; ht < H_ + KVH_; ht++) {
        const bool isQ = (ht < H_);
        const size_t src_i = rowbase + (isQ ? ht * 256 : 4096 + (ht - H_) * 128) + d;
        const float x = __bfloat162float(qkv[src_i]);
        float sq = x * x;
#pragma unroll
        for (int o = 32; o > 0; o >>= 1) sq += __shfl_down(sq, o);
        if ((d & 63) == 0) red[d >> 6] = sq;
        __syncthreads();
        const float var = (red[0] + red[1]) * (1.f / 128.f);
        const float xn = x * rsqrtf(var + EPS_) * (isQ ? qw : kw);
        sh[d] = xn;
        __syncthreads();
        const float rot = (d < 64) ? -sh[d + 64] : sh[d - 64];
        const float o = (xn * cv + rot * sv) * (isQ ? SCALE2_ : 1.f);
        if (isQ)
            qro[(((size_t)b * H_ + ht) * S_ + s) * D_ + d] = __float2bfloat16(o);
        else
            kro[(((size_t)b * KVH_ + (ht - H_)) * S_ + s) * D_ + d] = __float2bfloat16(o);
    }
}

// ---------------------------------------------------------------------------
// MFMA causal GQA flash attention + sigmoid gate (r18 best, ~93 us).
// grid = (16, B*H), 256 thr. 4 waves x 16 q-rows; KV tile = 64,
// single-buffered (42.5 KB -> 3 blocks/CU). Paired q-tiles {31-bx, bx};
// DPP log2 softmax (scale pre-folded into Q); T13 defer-rescale;
// setprio MFMA. Output into qkv's dead q-columns.
// ---------------------------------------------------------------------------
__global__ __launch_bounds__(256, 4) void flash_mfma(const short* __restrict__ qro,
                                                     const short* __restrict__ kro,
                                                     const short* __restrict__ vt,
                                                     short* __restrict__ qkv) {
    __shared__ __align__(16) short Ks[64][128];      // 16 KB, slot-swizzled
    __shared__ __align__(16) short Vs[128][64];      // 16 KB, slot-swizzled
    __shared__ __align__(16) short Pl[4][16][84];    // 10.5 KB

    const int tid = threadIdx.x;
    const int w = tid >> 6, l = tid & 63;
    const int lr = l & 15, g = l >> 4;
    const int bx = blockIdx.x;                       // 0..15
    const int bh = blockIdx.y;
    const int b = bh >> 4, h = bh & 15;
    const int kvh = h >> 1;

    const short* qbase = qro + (size_t)(b * H_ + h) * S_ * D_;
    const short* kbase = kro + (size_t)(b * KVH_ + kvh) * S_ * D_;
    const short* vbase = vt + (size_t)(b * KVH_ + kvh) * D_ * S_;

    auto stage = [&](int kt) {
        const int kb0 = kt * 64;
#pragma unroll
        for (int i = 0; i < 4; i++) {
            const int li = w * 4 + i;
            {
                const int r = li * 4 + (l >> 4);
                const int sgk = (l & 15) ^ (r & 7);
                gl_lds16(kbase + (size_t)(kb0 + r) * D_ + sgk * 8, &Ks[li * 4][0]);
            }
            {
                const int r = li * 8 + (l >> 3);
                const int sgv = (l & 7) ^ (r & 7);
                gl_lds16(vbase + (size_t)r * S_ + kb0 + sgv * 8, &Vs[li * 8][0]);
            }
        }
    };

#pragma unroll 1
    for (int seg = 0; seg < 2; seg++) {
        const int qt = seg ? bx : (31 - bx);         // heavy tile first
        const int q0 = qt * 64;
        const int qw0 = q0 + w * 16;

        s8v qa[4];
#pragma unroll
        for (int kc = 0; kc < 4; kc++)
            qa[kc] = *(const s8v*)(qbase + (size_t)(qw0 + lr) * D_ + kc * 32 + g * 8);

        f4v oacc[8];
#pragma unroll
        for (int i = 0; i < 8; i++) oacc[i] = (f4v)0.f;
        float m[4] = {-3e38f, -3e38f, -3e38f, -3e38f};
        float lsum[4] = {0.f, 0.f, 0.f, 0.f};

        const int nkt = qt + 1;
        for (int kt = 0; kt < nkt; kt++) {
            stage(kt);                               // prev reads done (trailing barrier)
            __syncthreads();                         // drains vmcnt -> K/V resident
            const int kb0 = kt * 64;

            // ---- QK^T: S[16 q][64 keys] (log2 domain, scale in Q) ----
            f4v sacc[4];
#pragma unroll
            for (int ni = 0; ni < 4; ni++) sacc[ni] = (f4v)0.f;
            __builtin_amdgcn_s_setprio(1);
#pragma unroll
            for (int ni = 0; ni < 4; ni++) {
                const int r = ni * 16 + lr;
#pragma unroll
                for (int kc = 0; kc < 4; kc++) {
                    const int ph = (kc * 4 + g) ^ (r & 7);
                    const s8v kb = *(const s8v*)&Ks[r][ph * 8];
                    sacc[ni] = MFMA(qa[kc], kb, sacc[ni]);
                }
            }
            __builtin_amdgcn_s_setprio(0);

            // ---- online softmax (log2), DPP reductions, defer-rescale ----
            const bool masked = (kt == qt);
            float p[4][4], tmax[4];
#pragma unroll
            for (int j = 0; j < 4; j++) {
                float v0 = -3e38f;
#pragma unroll
                for (int ni = 0; ni < 4; ni++) {
                    float sc = sacc[ni][j];
                    if (masked && (kb0 + ni * 16 + lr > qw0 + g * 4 + j)) sc = -3e38f;
                    p[ni][j] = sc;
                    v0 = fmaxf(v0, sc);
                }
                tmax[j] = v0;
            }
#pragma unroll
            for (int j = 0; j < 4; j++) tmax[j] = red16_max(tmax[j]);

            bool needb = false;
#pragma unroll
            for (int j = 0; j < 4; j++) needb = needb || (tmax[j] > m[j] + 7.f);
            const bool doresc = __any((int)needb);

            float cj[4], psum[4];
#pragma unroll
            for (int j = 0; j < 4; j++) {
                float mn = m[j];
                if (doresc) {
                    mn = fmaxf(m[j], tmax[j]);
                    cj[j] = __builtin_amdgcn_exp2f(m[j] - mn);
                    m[j] = mn;
                }
                float ps = 0.f;
#pragma unroll
                for (int ni = 0; ni < 4; ni++) {
                    const float e = __builtin_amdgcn_exp2f(p[ni][j] - mn);
                    p[ni][j] = e;
                    ps += e;
                }
                psum[j] = ps;
            }

            // ---- P -> bf16 via LDS transpose (overlaps the DPP sum) ----
#pragma unroll
            for (int ni = 0; ni < 4; ni++)
#pragma unroll
                for (int j = 0; j < 4; j++)
                    Pl[w][g * 4 + j][ni * 16 + lr] = (short)f2b(p[ni][j]);

#pragma unroll
            for (int j = 0; j < 4; j++) psum[j] = red16_sum(psum[j]);

            if (doresc) {
#pragma unroll
                for (int j = 0; j < 4; j++) lsum[j] = lsum[j] * cj[j] + psum[j];
#pragma unroll
                for (int di = 0; di < 8; di++)
#pragma unroll
                    for (int j = 0; j < 4; j++) oacc[di][j] *= cj[j];
            } else {
#pragma unroll
                for (int j = 0; j < 4; j++) lsum[j] += psum[j];
            }

            // ---- PV: O += P[16x64] @ V[64x128] ----
            __builtin_amdgcn_s_setprio(1);
#pragma unroll
            for (int kk = 0; kk < 2; kk++) {
                const s8v pa = *(const s8v*)&Pl[w][lr][kk * 32 + g * 8];
#pragma unroll
                for (int di = 0; di < 8; di++) {
                    const int r = di * 16 + lr;
                    const int ph = (kk * 4 + g) ^ (r & 7);
                    const s8v vb = *(const s8v*)&Vs[r][ph * 8];
                    oacc[di] = MFMA(pa, vb, oacc[di]);
                }
            }
            __builtin_amdgcn_s_setprio(0);
            __syncthreads();                         // reads done before next stage
        }

        // ---- epilogue: 1/l, sigmoid gate, store into qkv q-columns ----
        float linv[4];
#pragma unroll
        for (int j = 0; j < 4; j++) linv[j] = 1.f / lsum[j];
#pragma unroll
        for (int di = 0; di < 8; di++) {
            const int d = di * 16 + lr;
#pragma unroll
            for (int j = 0; j < 4; j++) {
                const int q = qw0 + g * 4 + j;
                const size_t base = (size_t)(b * S_ + q) * NQKV + h * 256;
                const float gate = b2f(qkv[base + 128 + d]);
                const float o = oacc[di][j] * linv[j] * (1.f / (1.f + __expf(-gate)));
                qkv[base + d] = (short)f2b(o);
            }
        }
    }
}

// ---------------------------------------------------------------------------
extern "C" void kernel_launch(void* const* d_in, const int* in_sizes, int n_in,
                              void* d_out, int out_size, void* d_ws, size_t ws_size,
                              hipStream_t stream) {
    const float* hs = (const float*)d_in[0];
    const float* cosb = (const float*)d_in[1];
    const float* sinb = (const float*)d_in[2];
    const float* Wq = (const float*)d_in[3];
    const float* Wk = (const float*)d_in[4];
    const float* Wv = (const float*)d_in[5];
    const float* Wo = (const float*)d_in[6];
    const float* qnw = (const float*)d_in[7];
    const float* knw = (const float*)d_in[8];
    float* out = (float*)d_out;

    short* ws = (short*)d_ws;
    short* Wot = ws;                  // 4194304
    short* Wt  = ws + 4194304;        // 12582912 (Wq^T rows 0..4095, Wk^T 4096.., Wv^T 5120..)
    short* hsb = ws + 16777216;       // 8388608
    short* qkv = ws + 25165824;       // 25165824  (total = 50331648 shorts = 96 MiB)
    // reuse after QKV gemm:
    short* qro = Wt;                  // 8388608
    short* kro = Wt + 8388608;        // 4194304
    short* vtb = hsb;                 // 4194304

    const int M = B_ * S_;
    const dim3 t32x8(32, 8, 1);

    // bf16 conversions / transposes
    f2bf_kernel<<<8192, 256, 0, stream>>>(hs, hsb, 2097152);
    qkvw_transpose<<<dim3(192, 64), t32x8, 0, stream>>>(Wq, Wk, Wv, Wt);
    transpose_conv<<<dim3(64, 64), t32x8, 0, stream>>>(Wo, Wot, 2048, 2048);

    // merged QKV projection: 256x384-tile 3-buffer MFMA GEMM,
    // grid (16,16) = 256 blocks = exactly one CU round (no tail)
    gemm256<<<dim3(16, 16), 512, 0, stream>>>(hsb, Wt, qkv, M, NQKV, HID_);

    // fused RMSNorm + RoPE, one block per (b,s), cos/sin loaded once
    norm_rope<<<dim3(B_ * S_), 128, 0, stream>>>((const bf16*)qkv, qnw, knw,
                                                 cosb, sinb, (bf16*)qro, (bf16*)kro);

    // V transpose to [head][D][S]
    transpose_v<<<dim3(64, 4, 16), t32x8, 0, stream>>>(qkv + 5120, vtb);

    // causal GQA attention + gate (writes into qkv q-columns), paired q-tiles
    flash_mfma<<<dim3(16, 32), 256, 0, stream>>>(qro, kro, vtb, qkv);

    // output projection (fp32 out): 256x128-tile 3-buffer pipeline, 1 blk/CU
    gemm_wo<<<dim3(16, 16), 512, 0, stream>>>(qkv, Wot, out, M, HID_, 2048);
}

// Round 20
// 296.328 us; speedup vs baseline: 1.0975x; 1.0975x over previous
//
#include <hip/hip_runtime.h>
#include <hip/hip_bf16.h>

#define B_ 2
#define S_ 2048
#define HID_ 2048
#define H_ 16
#define KVH_ 8
#define D_ 128
#define G_ 2
#define EPS_ 1e-6f
#define SCALE_ 0.08838834764831845f
// SCALE * log2(e): scores computed directly in log2 domain (folded into Q)
#define SCALE2_ 0.1275313760443445f
#define NQKV 6144

typedef __hip_bfloat16 bf16;
typedef __attribute__((ext_vector_type(8))) short s8v;   // 8 bf16 = 4 VGPR
typedef __attribute__((ext_vector_type(4))) float f4v;   // MFMA C/D

__device__ __forceinline__ unsigned short f2b(float f) {
    __hip_bfloat16 h = __float2bfloat16(f);
    return *reinterpret_cast<unsigned short*>(&h);
}
__device__ __forceinline__ float b2f(short u) {
    unsigned int x = ((unsigned int)(unsigned short)u) << 16;
    return __builtin_bit_cast(float, x);
}

__device__ __forceinline__ f4v MFMA(s8v a, s8v b, f4v c) {
    return __builtin_amdgcn_mfma_f32_16x16x32_bf16(a, b, c, 0, 0, 0);
}

__device__ __forceinline__ void gl_lds16(const void* g, void* l) {
    __builtin_amdgcn_global_load_lds(
        (const __attribute__((address_space(1))) void*)g,
        (__attribute__((address_space(3))) void*)l, 16, 0, 0);
}

__device__ __forceinline__ void cstore(float* p, float v) { *p = v; }
__device__ __forceinline__ void cstore(short* p, float v) { *p = (short)f2b(v); }

// ---- DPP 16-lane butterfly reduction (VALU, no LDS swizzle) ----
template <int CTRL>
__device__ __forceinline__ float dpp_f(float x) {
    return __builtin_bit_cast(float,
        __builtin_amdgcn_update_dpp(0, __builtin_bit_cast(int, x), CTRL, 0xF, 0xF, true));
}
__device__ __forceinline__ float red16_max(float v) {
    v = fmaxf(v, dpp_f<0xB1>(v));
    v = fmaxf(v, dpp_f<0x4E>(v));
    v = fmaxf(v, dpp_f<0x124>(v));
    v = fmaxf(v, dpp_f<0x128>(v));
    return v;
}
__device__ __forceinline__ float red16_sum(float v) {
    v += dpp_f<0xB1>(v);
    v += dpp_f<0x4E>(v);
    v += dpp_f<0x124>(v);
    v += dpp_f<0x128>(v);
    return v;
}

// ---------------------------------------------------------------------------
// fp32 -> bf16 bulk convert (vectorized)
// ---------------------------------------------------------------------------
__global__ __launch_bounds__(256) void f2bf_kernel(const float* __restrict__ in,
                                                   short* __restrict__ out, int n4) {
    int i = blockIdx.x * 256 + threadIdx.x;
    if (i >= n4) return;
    const float4 v = *(const float4*)(in + (size_t)i * 4);
    ushort4 o;
    o.x = f2b(v.x); o.y = f2b(v.y); o.z = f2b(v.z); o.w = f2b(v.w);
    *(ushort4*)(out + (size_t)i * 4) = o;
}

// ---------------------------------------------------------------------------
// ALL weight transposes in one launch:
//   bx <  192: [Wq|Wk|Wv] columns -> Wt[6144][2048] bf16
//   bx >= 192: Wo columns        -> Wot[2048][2048] bf16
// ---------------------------------------------------------------------------
__global__ __launch_bounds__(256) void w_transpose_all(const float* __restrict__ Wq,
                                                       const float* __restrict__ Wk,
                                                       const float* __restrict__ Wv,
                                                       const float* __restrict__ Wo,
                                                       short* __restrict__ outQKV,
                                                       short* __restrict__ outWo) {
    __shared__ short t[32][33];
    const int bx = blockIdx.x;
    const int k0 = blockIdx.y * 32;
    const float* src;
    short* out;
    int scol, sN, n0;
    if (bx < 192) {
        n0 = bx * 32;
        if (n0 < 4096)      { src = Wq; scol = n0;        sN = 4096; }
        else if (n0 < 5120) { src = Wk; scol = n0 - 4096; sN = 1024; }
        else                { src = Wv; scol = n0 - 5120; sN = 1024; }
        out = outQKV;
    } else {
        n0 = (bx - 192) * 32;
        src = Wo; scol = n0; sN = 2048;
        out = outWo;
    }
    const int tx = threadIdx.x, ty = threadIdx.y;
#pragma unroll
    for (int j = 0; j < 4; j++) {
        const int r = ty + j * 8;
        t[r][tx] = (short)f2b(src[(size_t)(k0 + r) * sN + scol + tx]);
    }
    __syncthreads();
#pragma unroll
    for (int j = 0; j < 4; j++) {
        const int r = ty + j * 8;
        out[(size_t)(n0 + r) * HID_ + k0 + tx] = t[tx][r];
    }
}

// ---------------------------------------------------------------------------
// V transpose per head: qkv v-columns -> vt[(b*KVH+kvh)][D][S]
// ---------------------------------------------------------------------------
__global__ __launch_bounds__(256) void transpose_v(const short* __restrict__ in,
                                                   short* __restrict__ out) {
    __shared__ short t[32][33];
    const int s0 = blockIdx.x * 32, d0 = blockIdx.y * 32, bk = blockIdx.z;
    const int b = bk / KVH_, kvh = bk % KVH_;
    const short* ip = in + (size_t)b * S_ * NQKV + kvh * D_;
    const int tx = threadIdx.x, ty = threadIdx.y;
#pragma unroll
    for (int j = 0; j < 4; j++) {
        const int r = ty + j * 8;
        t[r][tx] = ip[(size_t)(s0 + r) * NQKV + d0 + tx];
    }
    __syncthreads();
#pragma unroll
    for (int j = 0; j < 4; j++) {
        const int r = ty + j * 8;
        out[((size_t)bk * D_ + d0 + r) * S_ + s0 + tx] = t[tx][r];
    }
}

// ---------------------------------------------------------------------------
// 256x256 deep-pipelined MFMA GEMM (B^T form) -- r8/r15/r18 best (126 us).
// BK=32, 8 waves (2M x 4N), 3 LDS buffers, counted vmcnt(4) gate.
// ---------------------------------------------------------------------------
__global__ __launch_bounds__(512, 2) void gemm256(const short* __restrict__ A,
                                                  const short* __restrict__ Bt,
                                                  short* __restrict__ C,
                                                  int M, int N, int K) {
    __shared__ __align__(16) short As[3][256][32];   // 48 KB
    __shared__ __align__(16) short Bs[3][256][32];   // 48 KB
    const int tid = threadIdx.x;
    const int w = tid >> 6, l = tid & 63;
    const int lr = l & 15, g = l >> 4;
    const int nwg = gridDim.x * gridDim.y;
    int bid = blockIdx.y * gridDim.x + blockIdx.x;
    bid = (bid & 7) * (nwg >> 3) + (bid >> 3);       // XCD swizzle (nwg%8==0)
    const int bx = bid % gridDim.x, by = bid / gridDim.x;
    const int row0 = by * 256, col0 = bx * 256;
    const int wr = w >> 2, wc = w & 3;               // 2 x 4 wave grid

    f4v acc[8][4];
#pragma unroll
    for (int i = 0; i < 8; i++)
#pragma unroll
        for (int j = 0; j < 4; j++) acc[i][j] = (f4v)0.f;

    const int srow = l >> 2;
    const int schunk = (l & 3) ^ ((l >> 3) & 3);     // pre-swizzled source chunk
    const int rdslot = (g ^ ((lr >> 1) & 3)) * 8;    // swizzled read slot (elems)

    auto stageA = [&](int buf, int t) {
        const int kt = t * 32;
#pragma unroll
        for (int i = 0; i < 2; i++) {
            const int rb = w * 32 + i * 16;
            gl_lds16(A + (size_t)(row0 + rb + srow) * K + kt + schunk * 8,
                     &As[buf][rb][0]);
        }
    };
    auto stageB = [&](int buf, int t) {
        const int kt = t * 32;
#pragma unroll
        for (int i = 0; i < 2; i++) {
            const int rb = w * 32 + i * 16;
            gl_lds16(Bt + (size_t)(col0 + rb + srow) * K + kt + schunk * 8,
                     &Bs[buf][rb][0]);
        }
    };

    const int nt = K >> 5;                           // 64 tiles at K=2048
    stageA(0, 0); stageB(0, 0);
    stageA(1, 1); stageB(1, 1);

#pragma unroll 1
    for (int t = 0; t < nt; t++) {
        const int buf = t % 3;
        const int nbuf = (t + 2) % 3;

        __builtin_amdgcn_sched_barrier(0);
        if (t + 1 < nt) {
            asm volatile("s_waitcnt vmcnt(4)" ::: "memory");
        } else {
            asm volatile("s_waitcnt vmcnt(0)" ::: "memory");
        }
        __builtin_amdgcn_sched_barrier(0);
        __builtin_amdgcn_s_barrier();
        __builtin_amdgcn_sched_barrier(0);

        // phase 0: B frags + A rows 0-63, stage A of t+2, MFMA
        s8v b[4], a[4];
#pragma unroll
        for (int ni = 0; ni < 4; ni++)
            b[ni] = *(const s8v*)&Bs[buf][wc * 64 + ni * 16 + lr][rdslot];
#pragma unroll
        for (int mi = 0; mi < 4; mi++)
            a[mi] = *(const s8v*)&As[buf][wr * 128 + mi * 16 + lr][rdslot];
        if (t + 2 < nt) stageA(nbuf, t + 2);
        __builtin_amdgcn_s_setprio(1);
#pragma unroll
        for (int mi = 0; mi < 4; mi++)
#pragma unroll
            for (int ni = 0; ni < 4; ni++)
                acc[mi][ni] = MFMA(a[mi], b[ni], acc[mi][ni]);
        __builtin_amdgcn_s_setprio(0);
        __builtin_amdgcn_s_barrier();
        __builtin_amdgcn_sched_barrier(0);

        // phase 1: A rows 64-127, stage B of t+2, MFMA
        s8v a2[4];
#pragma unroll
        for (int mi = 0; mi < 4; mi++)
            a2[mi] = *(const s8v*)&As[buf][wr * 128 + (4 + mi) * 16 + lr][rdslot];
        if (t + 2 < nt) stageB(nbuf, t + 2);
        __builtin_amdgcn_s_setprio(1);
#pragma unroll
        for (int mi = 0; mi < 4; mi++)
#pragma unroll
            for (int ni = 0; ni < 4; ni++)
                acc[4 + mi][ni] = MFMA(a2[mi], b[ni], acc[4 + mi][ni]);
        __builtin_amdgcn_s_setprio(0);
    }

#pragma unroll
    for (int mi = 0; mi < 8; mi++)
#pragma unroll
        for (int ni = 0; ni < 4; ni++) {
            const int row = row0 + wr * 128 + mi * 16 + g * 4;
            const int col = col0 + wc * 64 + ni * 16 + lr;
#pragma unroll
            for (int j = 0; j < 4; j++)
                cstore(&C[(size_t)(row + j) * N + col], acc[mi][ni][j]);
        }
}

// ---------------------------------------------------------------------------
// Wo GEMM: 256x128 tile, 3-buffer counted-vmcnt pipeline, grid (16,16)=256
// blocks = exactly 1/CU. 8 waves (4M x 2N), per-wave 64x64 (4x4 frags).
// A read from qkv gated layout: (row,k) at row*NQKV + ((k>>7)<<8) + (k&127).
// ---------------------------------------------------------------------------
__global__ __launch_bounds__(512, 1) void gemm_wo(const short* __restrict__ A,
                                                  const short* __restrict__ Bt,
                                                  float* __restrict__ C,
                                                  int M, int N, int K) {
    __shared__ __align__(16) short As[3][256][32];   // 48 KB
    __shared__ __align__(16) short Bs[3][128][32];   // 24 KB
    const int tid = threadIdx.x;
    const int w = tid >> 6, l = tid & 63;
    const int lr = l & 15, g = l >> 4;
    const int nwg = gridDim.x * gridDim.y;
    int bid = blockIdx.y * gridDim.x + blockIdx.x;
    bid = (bid & 7) * (nwg >> 3) + (bid >> 3);       // XCD swizzle (nwg%8==0)
    const int bx = bid % gridDim.x, by = bid / gridDim.x;
    const int row0 = by * 256, col0 = bx * 128;
    const int wr = w >> 1, wc = w & 1;               // 4M x 2N wave grid

    f4v acc[4][4];
#pragma unroll
    for (int i = 0; i < 4; i++)
#pragma unroll
        for (int j = 0; j < 4; j++) acc[i][j] = (f4v)0.f;

    const int srow = l >> 2;
    const int schunk = (l & 3) ^ ((l >> 3) & 3);
    const int rdslot = (g ^ ((lr >> 1) & 3)) * 8;

    auto stage = [&](int buf, int t) {
        const int k = t * 32 + schunk * 8;
        const size_t goff = ((size_t)((k >> 7) << 8)) + (k & 127);
#pragma unroll
        for (int i = 0; i < 2; i++) {
            const int rb = w * 32 + i * 16;
            gl_lds16(A + (size_t)(row0 + rb + srow) * NQKV + goff, &As[buf][rb][0]);
        }
        gl_lds16(Bt + (size_t)(col0 + w * 16 + srow) * K + k, &Bs[buf][w * 16][0]);
    };

    const int nt = K >> 5;                           // 64
    stage(0, 0);
    stage(1, 1);

#pragma unroll 1
    for (int t = 0; t < nt; t++) {
        const int buf = t % 3;
        __builtin_amdgcn_sched_barrier(0);
        if (t + 1 < nt) {
            asm volatile("s_waitcnt vmcnt(3)" ::: "memory");
        } else {
            asm volatile("s_waitcnt vmcnt(0)" ::: "memory");
        }
        __builtin_amdgcn_sched_barrier(0);
        __builtin_amdgcn_s_barrier();
        __builtin_amdgcn_sched_barrier(0);

        s8v a[4], b[4];
#pragma unroll
        for (int mi = 0; mi < 4; mi++)
            a[mi] = *(const s8v*)&As[buf][wr * 64 + mi * 16 + lr][rdslot];
#pragma unroll
        for (int ni = 0; ni < 4; ni++)
            b[ni] = *(const s8v*)&Bs[buf][wc * 64 + ni * 16 + lr][rdslot];

        if (t + 2 < nt) stage((t + 2) % 3, t + 2);

        __builtin_amdgcn_s_setprio(1);
#pragma unroll
        for (int mi = 0; mi < 4; mi++)
#pragma unroll
            for (int ni = 0; ni < 4; ni++)
                acc[mi][ni] = MFMA(a[mi], b[ni], acc[mi][ni]);
        __builtin_amdgcn_s_setprio(0);
    }

#pragma unroll
    for (int mi = 0; mi < 4; mi++)
#pragma unroll
        for (int ni = 0; ni < 4; ni++) {
            const int row = row0 + wr * 64 + mi * 16 + g * 4;
            const int col = col0 + wc * 64 + ni * 16 + lr;
#pragma unroll
            for (int j = 0; j < 4; j++)
                cstore(&C[(size_t)(row + j) * N + col], acc[mi][ni][j]);
        }
}

// ---------------------------------------------------------------------------
// Fused RMSNorm + RoPE, one block per (b,s): cos/sin/norm-weights loaded
// ONCE, then loop the 24 heads (16 Q + 8 K).
// ---------------------------------------------------------------------------
__global__ __launch_bounds__(128) void norm_rope(const bf16* __restrict__ qkv,
                                                 const float* __restrict__ qnw,
                                                 const float* __restrict__ knw,
                                                 const float* __restrict__ cosb,
                                                 const float* __restrict__ sinb,
                                                 bf16* __restrict__ qro,
                                                 bf16* __restrict__ kro) {
    const int bs = blockIdx.x;                   // 0..B*S-1
    const int s = bs % S_;
    const int b = bs / S_;
    const int d = threadIdx.x;

    __shared__ float red[2];
    __shared__ float sh[128];

    const size_t cs_i = ((size_t)b * S_ + s) * D_ + d;
    const float cv = cosb[cs_i], sv = sinb[cs_i];
    const float qw = qnw[d], kw = knw[d];
    const size_t rowbase = (size_t)(b * S_ + s) * NQKV;

#pragma unroll 1
    for (int ht = 0; ht < H_ + KVH_; ht++) {
        const bool isQ = (ht < H_);
        const size_t src_i = rowbase + (isQ ? ht * 256 : 4096 + (ht - H_) * 128) + d;
        const float x = __bfloat162float(qkv[src_i]);
        float sq = x * x;
#pragma unroll
        for (int o = 32; o > 0; o >>= 1) sq += __shfl_down(sq, o);
        if ((d & 63) == 0) red[d >> 6] = sq;
        __syncthreads();
        const float var = (red[0] + red[1]) * (1.f / 128.f);
        const float xn = x * rsqrtf(var + EPS_) * (isQ ? qw : kw);
        sh[d] = xn;
        __syncthreads();
        const float rot = (d < 64) ? -sh[d + 64] : sh[d - 64];
        const float o = (xn * cv + rot * sv) * (isQ ? SCALE2_ : 1.f);
        if (isQ)
            qro[(((size_t)b * H_ + ht) * S_ + s) * D_ + d] = __float2bfloat16(o);
        else
            kro[(((size_t)b * KVH_ + (ht - H_)) * S_ + s) * D_ + d] = __float2bfloat16(o);
    }
}

// ---------------------------------------------------------------------------
// MFMA causal GQA flash attention + sigmoid gate (r18 best, ~93 us).
// grid = (16, B*H), 256 thr. 4 waves x 16 q-rows; KV tile = 64,
// single-buffered (42.5 KB -> 3 blocks/CU). Paired q-tiles {31-bx, bx};
// DPP log2 softmax (scale pre-folded into Q); T13 defer-rescale;
// setprio MFMA. Output into qkv's dead q-columns.
// ---------------------------------------------------------------------------
__global__ __launch_bounds__(256, 4) void flash_mfma(const short* __restrict__ qro,
                                                     const short* __restrict__ kro,
                                                     const short* __restrict__ vt,
                                                     short* __restrict__ qkv) {
    __shared__ __align__(16) short Ks[64][128];      // 16 KB, slot-swizzled
    __shared__ __align__(16) short Vs[128][64];      // 16 KB, slot-swizzled
    __shared__ __align__(16) short Pl[4][16][84];    // 10.5 KB

    const int tid = threadIdx.x;
    const int w = tid >> 6, l = tid & 63;
    const int lr = l & 15, g = l >> 4;
    const int bx = blockIdx.x;                       // 0..15
    const int bh = blockIdx.y;
    const int b = bh >> 4, h = bh & 15;
    const int kvh = h >> 1;

    const short* qbase = qro + (size_t)(b * H_ + h) * S_ * D_;
    const short* kbase = kro + (size_t)(b * KVH_ + kvh) * S_ * D_;
    const short* vbase = vt + (size_t)(b * KVH_ + kvh) * D_ * S_;

    auto stage = [&](int kt) {
        const int kb0 = kt * 64;
#pragma unroll
        for (int i = 0; i < 4; i++) {
            const int li = w * 4 + i;
            {
                const int r = li * 4 + (l >> 4);
                const int sgk = (l & 15) ^ (r & 7);
                gl_lds16(kbase + (size_t)(kb0 + r) * D_ + sgk * 8, &Ks[li * 4][0]);
            }
            {
                const int r = li * 8 + (l >> 3);
                const int sgv = (l & 7) ^ (r & 7);
                gl_lds16(vbase + (size_t)r * S_ + kb0 + sgv * 8, &Vs[li * 8][0]);
            }
        }
    };

#pragma unroll 1
    for (int seg = 0; seg < 2; seg++) {
        const int qt = seg ? bx : (31 - bx);         // heavy tile first
        const int q0 = qt * 64;
        const int qw0 = q0 + w * 16;

        s8v qa[4];
#pragma unroll
        for (int kc = 0; kc < 4; kc++)
            qa[kc] = *(const s8v*)(qbase + (size_t)(qw0 + lr) * D_ + kc * 32 + g * 8);

        f4v oacc[8];
#pragma unroll
        for (int i = 0; i < 8; i++) oacc[i] = (f4v)0.f;
        float m[4] = {-3e38f, -3e38f, -3e38f, -3e38f};
        float lsum[4] = {0.f, 0.f, 0.f, 0.f};

        const int nkt = qt + 1;
        for (int kt = 0; kt < nkt; kt++) {
            stage(kt);                               // prev reads done (trailing barrier)
            __syncthreads();                         // drains vmcnt -> K/V resident
            const int kb0 = kt * 64;

            // ---- QK^T: S[16 q][64 keys] (log2 domain, scale in Q) ----
            f4v sacc[4];
#pragma unroll
            for (int ni = 0; ni < 4; ni++) sacc[ni] = (f4v)0.f;
            __builtin_amdgcn_s_setprio(1);
#pragma unroll
            for (int ni = 0; ni < 4; ni++) {
                const int r = ni * 16 + lr;
#pragma unroll
                for (int kc = 0; kc < 4; kc++) {
                    const int ph = (kc * 4 + g) ^ (r & 7);
                    const s8v kb = *(const s8v*)&Ks[r][ph * 8];
                    sacc[ni] = MFMA(qa[kc], kb, sacc[ni]);
                }
            }
            __builtin_amdgcn_s_setprio(0);

            // ---- online softmax (log2), DPP reductions, defer-rescale ----
            const bool masked = (kt == qt);
            float p[4][4], tmax[4];
#pragma unroll
            for (int j = 0; j < 4; j++) {
                float v0 = -3e38f;
#pragma unroll
                for (int ni = 0; ni < 4; ni++) {
                    float sc = sacc[ni][j];
                    if (masked && (kb0 + ni * 16 + lr > qw0 + g * 4 + j)) sc = -3e38f;
                    p[ni][j] = sc;
                    v0 = fmaxf(v0, sc);
                }
                tmax[j] = v0;
            }
#pragma unroll
            for (int j = 0; j < 4; j++) tmax[j] = red16_max(tmax[j]);

            bool needb = false;
#pragma unroll
            for (int j = 0; j < 4; j++) needb = needb || (tmax[j] > m[j] + 7.f);
            const bool doresc = __any((int)needb);

            float cj[4], psum[4];
#pragma unroll
            for (int j = 0; j < 4; j++) {
                float mn = m[j];
                if (doresc) {
                    mn = fmaxf(m[j], tmax[j]);
                    cj[j] = __builtin_amdgcn_exp2f(m[j] - mn);
                    m[j] = mn;
                }
                float ps = 0.f;
#pragma unroll
                for (int ni = 0; ni < 4; ni++) {
                    const float e = __builtin_amdgcn_exp2f(p[ni][j] - mn);
                    p[ni][j] = e;
                    ps += e;
                }
                psum[j] = ps;
            }

            // ---- P -> bf16 via LDS transpose (overlaps the DPP sum) ----
#pragma unroll
            for (int ni = 0; ni < 4; ni++)
#pragma unroll
                for (int j = 0; j < 4; j++)
                    Pl[w][g * 4 + j][ni * 16 + lr] = (short)f2b(p[ni][j]);

#pragma unroll
            for (int j = 0; j < 4; j++) psum[j] = red16_sum(psum[j]);

            if (doresc) {
#pragma unroll
                for (int j = 0; j < 4; j++) lsum[j] = lsum[j] * cj[j] + psum[j];
#pragma unroll
                for (int di = 0; di < 8; di++)
#pragma unroll
                    for (int j = 0; j < 4; j++) oacc[di][j] *= cj[j];
            } else {
#pragma unroll
                for (int j = 0; j < 4; j++) lsum[j] += psum[j];
            }

            // ---- PV: O += P[16x64] @ V[64x128] ----
            __builtin_amdgcn_s_setprio(1);
#pragma unroll
            for (int kk = 0; kk < 2; kk++) {
                const s8v pa = *(const s8v*)&Pl[w][lr][kk * 32 + g * 8];
#pragma unroll
                for (int di = 0; di < 8; di++) {
                    const int r = di * 16 + lr;
                    const int ph = (kk * 4 + g) ^ (r & 7);
                    const s8v vb = *(const s8v*)&Vs[r][ph * 8];
                    oacc[di] = MFMA(pa, vb, oacc[di]);
                }
            }
            __builtin_amdgcn_s_setprio(0);
            __syncthreads();                         // reads done before next stage
        }

        // ---- epilogue: 1/l, sigmoid gate, store into qkv q-columns ----
        float linv[4];
#pragma unroll
        for (int j = 0; j < 4; j++) linv[j] = 1.f / lsum[j];
#pragma unroll
        for (int di = 0; di < 8; di++) {
            const int d = di * 16 + lr;
#pragma unroll
            for (int j = 0; j < 4; j++) {
                const int q = qw0 + g * 4 + j;
                const size_t base = (size_t)(b * S_ + q) * NQKV + h * 256;
                const float gate = b2f(qkv[base + 128 + d]);
                const float o = oacc[di][j] * linv[j] * (1.f / (1.f + __expf(-gate)));
                qkv[base + d] = (short)f2b(o);
            }
        }
    }
}

// ---------------------------------------------------------------------------
extern "C" void kernel_launch(void* const* d_in, const int* in_sizes, int n_in,
                              void* d_out, int out_size, void* d_ws, size_t ws_size,
                              hipStream_t stream) {
    const float* hs = (const float*)d_in[0];
    const float* cosb = (const float*)d_in[1];
    const float* sinb = (const float*)d_in[2];
    const float* Wq = (const float*)d_in[3];
    const float* Wk = (const float*)d_in[4];
    const float* Wv = (const float*)d_in[5];
    const float* Wo = (const float*)d_in[6];
    const float* qnw = (const float*)d_in[7];
    const float* knw = (const float*)d_in[8];
    float* out = (float*)d_out;

    short* ws = (short*)d_ws;
    short* Wot = ws;                  // 4194304
    short* Wt  = ws + 4194304;        // 12582912 (Wq^T rows 0..4095, Wk^T 4096.., Wv^T 5120..)
    short* hsb = ws + 16777216;       // 8388608
    short* qkv = ws + 25165824;       // 25165824  (total = 50331648 shorts = 96 MiB)
    // reuse after QKV gemm:
    short* qro = Wt;                  // 8388608
    short* kro = Wt + 8388608;        // 4194304
    short* vtb = hsb;                 // 4194304

    const int M = B_ * S_;
    const dim3 t32x8(32, 8, 1);

    // bf16 conversions / transposes (weights in ONE launch)
    f2bf_kernel<<<8192, 256, 0, stream>>>(hs, hsb, 2097152);
    w_transpose_all<<<dim3(256, 64), t32x8, 0, stream>>>(Wq, Wk, Wv, Wo, Wt, Wot);

    // merged QKV projection: 256^2 3-buffer deep-pipelined MFMA GEMM
    gemm256<<<dim3(24, 16), 512, 0, stream>>>(hsb, Wt, qkv, M, NQKV, HID_);

    // fused RMSNorm + RoPE, one block per (b,s), cos/sin loaded once
    norm_rope<<<dim3(B_ * S_), 128, 0, stream>>>((const bf16*)qkv, qnw, knw,
                                                 cosb, sinb, (bf16*)qro, (bf16*)kro);

    // V transpose to [head][D][S]
    transpose_v<<<dim3(64, 4, 16), t32x8, 0, stream>>>(qkv + 5120, vtb);

    // causal GQA attention + gate (writes into qkv q-columns), paired q-tiles
    flash_mfma<<<dim3(16, 32), 256, 0, stream>>>(qro, kro, vtb, qkv);

    // output projection (fp32 out): 256x128-tile 3-buffer pipeline, 1 blk/CU
    gemm_wo<<<dim3(16, 16), 512, 0, stream>>>(qkv, Wot, out, M, HID_, 2048);
}

// Round 21
// 290.581 us; speedup vs baseline: 1.1192x; 1.0198x over previous
//
#include <hip/hip_runtime.h>
#include <hip/hip_bf16.h>

#define B_ 2
#define S_ 2048
#define HID_ 2048
#define H_ 16
#define KVH_ 8
#define D_ 128
#define G_ 2
#define EPS_ 1e-6f
#define SCALE_ 0.08838834764831845f
// SCALE * log2(e): scores computed directly in log2 domain (folded into Q)
#define SCALE2_ 0.1275313760443445f
#define NQKV 6144

typedef __hip_bfloat16 bf16;
typedef __attribute__((ext_vector_type(8))) short s8v;   // 8 bf16 = 4 VGPR
typedef __attribute__((ext_vector_type(4))) float f4v;   // MFMA C/D

__device__ __forceinline__ unsigned short f2b(float f) {
    __hip_bfloat16 h = __float2bfloat16(f);
    return *reinterpret_cast<unsigned short*>(&h);
}
__device__ __forceinline__ float b2f(short u) {
    unsigned int x = ((unsigned int)(unsigned short)u) << 16;
    return __builtin_bit_cast(float, x);
}

__device__ __forceinline__ f4v MFMA(s8v a, s8v b, f4v c) {
    return __builtin_amdgcn_mfma_f32_16x16x32_bf16(a, b, c, 0, 0, 0);
}

__device__ __forceinline__ void gl_lds16(const void* g, void* l) {
    __builtin_amdgcn_global_load_lds(
        (const __attribute__((address_space(1))) void*)g,
        (__attribute__((address_space(3))) void*)l, 16, 0, 0);
}

__device__ __forceinline__ void cstore(float* p, float v) { *p = v; }
__device__ __forceinline__ void cstore(short* p, float v) { *p = (short)f2b(v); }

// ---- DPP 16-lane butterfly reduction (VALU, no LDS swizzle) ----
template <int CTRL>
__device__ __forceinline__ float dpp_f(float x) {
    return __builtin_bit_cast(float,
        __builtin_amdgcn_update_dpp(0, __builtin_bit_cast(int, x), CTRL, 0xF, 0xF, true));
}
__device__ __forceinline__ float red16_max(float v) {
    v = fmaxf(v, dpp_f<0xB1>(v));
    v = fmaxf(v, dpp_f<0x4E>(v));
    v = fmaxf(v, dpp_f<0x124>(v));
    v = fmaxf(v, dpp_f<0x128>(v));
    return v;
}
__device__ __forceinline__ float red16_sum(float v) {
    v += dpp_f<0xB1>(v);
    v += dpp_f<0x4E>(v);
    v += dpp_f<0x124>(v);
    v += dpp_f<0x128>(v);
    return v;
}

// ---------------------------------------------------------------------------
// Fused prep: blocks 0..8191 convert hidden_states fp32->bf16 (vectorized);
// blocks 8192..24575 transpose+convert all weights ([Wq|Wk|Wv] -> Wt,
// Wo -> Wot). Independent work merged into ONE launch so the two phases
// run concurrently and one launch gap disappears.
// ---------------------------------------------------------------------------
__global__ __launch_bounds__(256) void prep_all(const float* __restrict__ hs,
                                                const float* __restrict__ Wq,
                                                const float* __restrict__ Wk,
                                                const float* __restrict__ Wv,
                                                const float* __restrict__ Wo,
                                                short* __restrict__ hsb,
                                                short* __restrict__ outQKV,
                                                short* __restrict__ outWo) {
    __shared__ short t[32][33];
    const int blk = blockIdx.x;
    if (blk < 8192) {                                // f2bf role (8192*1024 = B*S*HID)
        const int i = blk * 256 + threadIdx.x;
        const float4 v = *(const float4*)(hs + (size_t)i * 4);
        ushort4 o;
        o.x = f2b(v.x); o.y = f2b(v.y); o.z = f2b(v.z); o.w = f2b(v.w);
        *(ushort4*)(hsb + (size_t)i * 4) = o;
        return;
    }
    const int widx = blk - 8192;                     // weight-transpose role
    const int bxw = widx & 255;
    const int k0 = (widx >> 8) * 32;
    const int tx = threadIdx.x & 31, ty = threadIdx.x >> 5;
    const float* src;
    short* out;
    int scol, sN, n0;
    if (bxw < 192) {
        n0 = bxw * 32;
        if (n0 < 4096)      { src = Wq; scol = n0;        sN = 4096; }
        else if (n0 < 5120) { src = Wk; scol = n0 - 4096; sN = 1024; }
        else                { src = Wv; scol = n0 - 5120; sN = 1024; }
        out = outQKV;
    } else {
        n0 = (bxw - 192) * 32;
        src = Wo; scol = n0; sN = 2048;
        out = outWo;
    }
#pragma unroll
    for (int j = 0; j < 4; j++) {
        const int r = ty + j * 8;
        t[r][tx] = (short)f2b(src[(size_t)(k0 + r) * sN + scol + tx]);
    }
    __syncthreads();
#pragma unroll
    for (int j = 0; j < 4; j++) {
        const int r = ty + j * 8;
        out[(size_t)(n0 + r) * HID_ + k0 + tx] = t[tx][r];
    }
}

// ---------------------------------------------------------------------------
// 256x256 deep-pipelined MFMA GEMM (B^T form) -- r8/r15/r18 best (126 us).
// BK=32, 8 waves (2M x 4N), 3 LDS buffers, counted vmcnt(4) gate.
// ---------------------------------------------------------------------------
__global__ __launch_bounds__(512, 2) void gemm256(const short* __restrict__ A,
                                                  const short* __restrict__ Bt,
                                                  short* __restrict__ C,
                                                  int M, int N, int K) {
    __shared__ __align__(16) short As[3][256][32];   // 48 KB
    __shared__ __align__(16) short Bs[3][256][32];   // 48 KB
    const int tid = threadIdx.x;
    const int w = tid >> 6, l = tid & 63;
    const int lr = l & 15, g = l >> 4;
    const int nwg = gridDim.x * gridDim.y;
    int bid = blockIdx.y * gridDim.x + blockIdx.x;
    bid = (bid & 7) * (nwg >> 3) + (bid >> 3);       // XCD swizzle (nwg%8==0)
    const int bx = bid % gridDim.x, by = bid / gridDim.x;
    const int row0 = by * 256, col0 = bx * 256;
    const int wr = w >> 2, wc = w & 3;               // 2 x 4 wave grid

    f4v acc[8][4];
#pragma unroll
    for (int i = 0; i < 8; i++)
#pragma unroll
        for (int j = 0; j < 4; j++) acc[i][j] = (f4v)0.f;

    const int srow = l >> 2;
    const int schunk = (l & 3) ^ ((l >> 3) & 3);     // pre-swizzled source chunk
    const int rdslot = (g ^ ((lr >> 1) & 3)) * 8;    // swizzled read slot (elems)

    auto stageA = [&](int buf, int t) {
        const int kt = t * 32;
#pragma unroll
        for (int i = 0; i < 2; i++) {
            const int rb = w * 32 + i * 16;
            gl_lds16(A + (size_t)(row0 + rb + srow) * K + kt + schunk * 8,
                     &As[buf][rb][0]);
        }
    };
    auto stageB = [&](int buf, int t) {
        const int kt = t * 32;
#pragma unroll
        for (int i = 0; i < 2; i++) {
            const int rb = w * 32 + i * 16;
            gl_lds16(Bt + (size_t)(col0 + rb + srow) * K + kt + schunk * 8,
                     &Bs[buf][rb][0]);
        }
    };

    const int nt = K >> 5;                           // 64 tiles at K=2048
    stageA(0, 0); stageB(0, 0);
    stageA(1, 1); stageB(1, 1);

#pragma unroll 1
    for (int t = 0; t < nt; t++) {
        const int buf = t % 3;
        const int nbuf = (t + 2) % 3;

        __builtin_amdgcn_sched_barrier(0);
        if (t + 1 < nt) {
            asm volatile("s_waitcnt vmcnt(4)" ::: "memory");
        } else {
            asm volatile("s_waitcnt vmcnt(0)" ::: "memory");
        }
        __builtin_amdgcn_sched_barrier(0);
        __builtin_amdgcn_s_barrier();
        __builtin_amdgcn_sched_barrier(0);

        // phase 0: B frags + A rows 0-63, stage A of t+2, MFMA
        s8v b[4], a[4];
#pragma unroll
        for (int ni = 0; ni < 4; ni++)
            b[ni] = *(const s8v*)&Bs[buf][wc * 64 + ni * 16 + lr][rdslot];
#pragma unroll
        for (int mi = 0; mi < 4; mi++)
            a[mi] = *(const s8v*)&As[buf][wr * 128 + mi * 16 + lr][rdslot];
        if (t + 2 < nt) stageA(nbuf, t + 2);
        __builtin_amdgcn_s_setprio(1);
#pragma unroll
        for (int mi = 0; mi < 4; mi++)
#pragma unroll
            for (int ni = 0; ni < 4; ni++)
                acc[mi][ni] = MFMA(a[mi], b[ni], acc[mi][ni]);
        __builtin_amdgcn_s_setprio(0);
        __builtin_amdgcn_s_barrier();
        __builtin_amdgcn_sched_barrier(0);

        // phase 1: A rows 64-127, stage B of t+2, MFMA
        s8v a2[4];
#pragma unroll
        for (int mi = 0; mi < 4; mi++)
            a2[mi] = *(const s8v*)&As[buf][wr * 128 + (4 + mi) * 16 + lr][rdslot];
        if (t + 2 < nt) stageB(nbuf, t + 2);
        __builtin_amdgcn_s_setprio(1);
#pragma unroll
        for (int mi = 0; mi < 4; mi++)
#pragma unroll
            for (int ni = 0; ni < 4; ni++)
                acc[4 + mi][ni] = MFMA(a2[mi], b[ni], acc[4 + mi][ni]);
        __builtin_amdgcn_s_setprio(0);
    }

#pragma unroll
    for (int mi = 0; mi < 8; mi++)
#pragma unroll
        for (int ni = 0; ni < 4; ni++) {
            const int row = row0 + wr * 128 + mi * 16 + g * 4;
            const int col = col0 + wc * 64 + ni * 16 + lr;
#pragma unroll
            for (int j = 0; j < 4; j++)
                cstore(&C[(size_t)(row + j) * N + col], acc[mi][ni][j]);
        }
}

// ---------------------------------------------------------------------------
// Wo GEMM: 256x128 tile, 3-buffer counted-vmcnt pipeline, grid (16,16)=256
// blocks = exactly 1/CU. 8 waves (4M x 2N), per-wave 64x64 (4x4 frags).
// A read from qkv gated layout: (row,k) at row*NQKV + ((k>>7)<<8) + (k&127).
// ---------------------------------------------------------------------------
__global__ __launch_bounds__(512, 1) void gemm_wo(const short* __restrict__ A,
                                                  const short* __restrict__ Bt,
                                                  float* __restrict__ C,
                                                  int M, int N, int K) {
    __shared__ __align__(16) short As[3][256][32];   // 48 KB
    __shared__ __align__(16) short Bs[3][128][32];   // 24 KB
    const int tid = threadIdx.x;
    const int w = tid >> 6, l = tid & 63;
    const int lr = l & 15, g = l >> 4;
    const int nwg = gridDim.x * gridDim.y;
    int bid = blockIdx.y * gridDim.x + blockIdx.x;
    bid = (bid & 7) * (nwg >> 3) + (bid >> 3);       // XCD swizzle (nwg%8==0)
    const int bx = bid % gridDim.x, by = bid / gridDim.x;
    const int row0 = by * 256, col0 = bx * 128;
    const int wr = w >> 1, wc = w & 1;               // 4M x 2N wave grid

    f4v acc[4][4];
#pragma unroll
    for (int i = 0; i < 4; i++)
#pragma unroll
        for (int j = 0; j < 4; j++) acc[i][j] = (f4v)0.f;

    const int srow = l >> 2;
    const int schunk = (l & 3) ^ ((l >> 3) & 3);
    const int rdslot = (g ^ ((lr >> 1) & 3)) * 8;

    auto stage = [&](int buf, int t) {
        const int k = t * 32 + schunk * 8;
        const size_t goff = ((size_t)((k >> 7) << 8)) + (k & 127);
#pragma unroll
        for (int i = 0; i < 2; i++) {
            const int rb = w * 32 + i * 16;
            gl_lds16(A + (size_t)(row0 + rb + srow) * NQKV + goff, &As[buf][rb][0]);
        }
        gl_lds16(Bt + (size_t)(col0 + w * 16 + srow) * K + k, &Bs[buf][w * 16][0]);
    };

    const int nt = K >> 5;                           // 64
    stage(0, 0);
    stage(1, 1);

#pragma unroll 1
    for (int t = 0; t < nt; t++) {
        const int buf = t % 3;
        __builtin_amdgcn_sched_barrier(0);
        if (t + 1 < nt) {
            asm volatile("s_waitcnt vmcnt(3)" ::: "memory");
        } else {
            asm volatile("s_waitcnt vmcnt(0)" ::: "memory");
        }
        __builtin_amdgcn_sched_barrier(0);
        __builtin_amdgcn_s_barrier();
        __builtin_amdgcn_sched_barrier(0);

        s8v a[4], b[4];
#pragma unroll
        for (int mi = 0; mi < 4; mi++)
            a[mi] = *(const s8v*)&As[buf][wr * 64 + mi * 16 + lr][rdslot];
#pragma unroll
        for (int ni = 0; ni < 4; ni++)
            b[ni] = *(const s8v*)&Bs[buf][wc * 64 + ni * 16 + lr][rdslot];

        if (t + 2 < nt) stage((t + 2) % 3, t + 2);

        __builtin_amdgcn_s_setprio(1);
#pragma unroll
        for (int mi = 0; mi < 4; mi++)
#pragma unroll
            for (int ni = 0; ni < 4; ni++)
                acc[mi][ni] = MFMA(a[mi], b[ni], acc[mi][ni]);
        __builtin_amdgcn_s_setprio(0);
    }

#pragma unroll
    for (int mi = 0; mi < 4; mi++)
#pragma unroll
        for (int ni = 0; ni < 4; ni++) {
            const int row = row0 + wr * 64 + mi * 16 + g * 4;
            const int col = col0 + wc * 64 + ni * 16 + lr;
#pragma unroll
            for (int j = 0; j < 4; j++)
                cstore(&C[(size_t)(row + j) * N + col], acc[mi][ni][j]);
        }
}

// ---------------------------------------------------------------------------
// Fused norm/RoPE + V-transpose in ONE launch (independent work, runs
// concurrently):
//   blocks 0..2047: RMSNorm+RoPE, TWO (b,s) rows per 256-thr block
//                   (per-half shared arrays; barriers uniform);
//   blocks 2048..6143: V transpose qkv v-cols -> vt[(b*KVH+kvh)][D][S].
// ---------------------------------------------------------------------------
__global__ __launch_bounds__(256) void norm_vtrans(const bf16* __restrict__ qkv,
                                                   const float* __restrict__ qnw,
                                                   const float* __restrict__ knw,
                                                   const float* __restrict__ cosb,
                                                   const float* __restrict__ sinb,
                                                   bf16* __restrict__ qro,
                                                   bf16* __restrict__ kro,
                                                   short* __restrict__ vt) {
    __shared__ float red[2][2];
    __shared__ float sh[2][128];
    __shared__ short t[32][33];
    const int blk = blockIdx.x;

    if (blk < 2048) {                                // norm+RoPE role
        const int half = threadIdx.x >> 7;
        const int d = threadIdx.x & 127;
        const int bs = blk * 2 + half;
        const int s = bs % S_;
        const int b = bs / S_;

        const size_t cs_i = ((size_t)b * S_ + s) * D_ + d;
        const float cv = cosb[cs_i], sv = sinb[cs_i];
        const float qw = qnw[d], kw = knw[d];
        const size_t rowbase = (size_t)(b * S_ + s) * NQKV;

#pragma unroll 1
        for (int ht = 0; ht < H_ + KVH_; ht++) {
            const bool isQ = (ht < H_);
            const size_t src_i = rowbase + (isQ ? ht * 256 : 4096 + (ht - H_) * 128) + d;
            const float x = __bfloat162float(qkv[src_i]);
            float sq = x * x;
#pragma unroll
            for (int o = 32; o > 0; o >>= 1) sq += __shfl_down(sq, o);
            if ((d & 63) == 0) red[half][d >> 6] = sq;
            __syncthreads();
            const float var = (red[half][0] + red[half][1]) * (1.f / 128.f);
            const float xn = x * rsqrtf(var + EPS_) * (isQ ? qw : kw);
            sh[half][d] = xn;
            __syncthreads();
            const float rot = (d < 64) ? -sh[half][d + 64] : sh[half][d - 64];
            const float o = (xn * cv + rot * sv) * (isQ ? SCALE2_ : 1.f);
            if (isQ)
                qro[(((size_t)b * H_ + ht) * S_ + s) * D_ + d] = __float2bfloat16(o);
            else
                kro[(((size_t)b * KVH_ + (ht - H_)) * S_ + s) * D_ + d] = __float2bfloat16(o);
        }
        return;
    }

    // V-transpose role
    const int widx = blk - 2048;                     // 0..4095
    const int s0 = (widx & 63) * 32;
    const int d0 = ((widx >> 6) & 3) * 32;
    const int bk = widx >> 8;                        // 0..15
    const int b = bk / KVH_, kvh = bk % KVH_;
    const short* ip = (const short*)qkv + (size_t)b * S_ * NQKV + 5120 + kvh * D_;
    const int tx = threadIdx.x & 31, ty = threadIdx.x >> 5;
#pragma unroll
    for (int j = 0; j < 4; j++) {
        const int r = ty + j * 8;
        t[r][tx] = ip[(size_t)(s0 + r) * NQKV + d0 + tx];
    }
    __syncthreads();
#pragma unroll
    for (int j = 0; j < 4; j++) {
        const int r = ty + j * 8;
        vt[((size_t)bk * D_ + d0 + r) * S_ + s0 + tx] = t[tx][r];
    }
}

// ---------------------------------------------------------------------------
// MFMA causal GQA flash attention + sigmoid gate (r18 best, ~93 us).
// grid = (16, B*H), 256 thr. 4 waves x 16 q-rows; KV tile = 64,
// single-buffered (42.5 KB -> 3 blocks/CU). Paired q-tiles {31-bx, bx};
// DPP log2 softmax (scale pre-folded into Q); T13 defer-rescale;
// setprio MFMA. Output into qkv's dead q-columns.
// ---------------------------------------------------------------------------
__global__ __launch_bounds__(256, 4) void flash_mfma(const short* __restrict__ qro,
                                                     const short* __restrict__ kro,
                                                     const short* __restrict__ vt,
                                                     short* __restrict__ qkv) {
    __shared__ __align__(16) short Ks[64][128];      // 16 KB, slot-swizzled
    __shared__ __align__(16) short Vs[128][64];      // 16 KB, slot-swizzled
    __shared__ __align__(16) short Pl[4][16][84];    // 10.5 KB

    const int tid = threadIdx.x;
    const int w = tid >> 6, l = tid & 63;
    const int lr = l & 15, g = l >> 4;
    const int bx = blockIdx.x;                       // 0..15
    const int bh = blockIdx.y;
    const int b = bh >> 4, h = bh & 15;
    const int kvh = h >> 1;

    const short* qbase = qro + (size_t)(b * H_ + h) * S_ * D_;
    const short* kbase = kro + (size_t)(b * KVH_ + kvh) * S_ * D_;
    const short* vbase = vt + (size_t)(b * KVH_ + kvh) * D_ * S_;

    auto stage = [&](int kt) {
        const int kb0 = kt * 64;
#pragma unroll
        for (int i = 0; i < 4; i++) {
            const int li = w * 4 + i;
            {
                const int r = li * 4 + (l >> 4);
                const int sgk = (l & 15) ^ (r & 7);
                gl_lds16(kbase + (size_t)(kb0 + r) * D_ + sgk * 8, &Ks[li * 4][0]);
            }
            {
                const int r = li * 8 + (l >> 3);
                const int sgv = (l & 7) ^ (r & 7);
                gl_lds16(vbase + (size_t)r * S_ + kb0 + sgv * 8, &Vs[li * 8][0]);
            }
        }
    };

#pragma unroll 1
    for (int seg = 0; seg < 2; seg++) {
        const int qt = seg ? bx : (31 - bx);         // heavy tile first
        const int q0 = qt * 64;
        const int qw0 = q0 + w * 16;

        s8v qa[4];
#pragma unroll
        for (int kc = 0; kc < 4; kc++)
            qa[kc] = *(const s8v*)(qbase + (size_t)(qw0 + lr) * D_ + kc * 32 + g * 8);

        f4v oacc[8];
#pragma unroll
        for (int i = 0; i < 8; i++) oacc[i] = (f4v)0.f;
        float m[4] = {-3e38f, -3e38f, -3e38f, -3e38f};
        float lsum[4] = {0.f, 0.f, 0.f, 0.f};

        const int nkt = qt + 1;
        for (int kt = 0; kt < nkt; kt++) {
            stage(kt);                               // prev reads done (trailing barrier)
            __syncthreads();                         // drains vmcnt -> K/V resident
            const int kb0 = kt * 64;

            // ---- QK^T: S[16 q][64 keys] (log2 domain, scale in Q) ----
            f4v sacc[4];
#pragma unroll
            for (int ni = 0; ni < 4; ni++) sacc[ni] = (f4v)0.f;
            __builtin_amdgcn_s_setprio(1);
#pragma unroll
            for (int ni = 0; ni < 4; ni++) {
                const int r = ni * 16 + lr;
#pragma unroll
                for (int kc = 0; kc < 4; kc++) {
                    const int ph = (kc * 4 + g) ^ (r & 7);
                    const s8v kb = *(const s8v*)&Ks[r][ph * 8];
                    sacc[ni] = MFMA(qa[kc], kb, sacc[ni]);
                }
            }
            __builtin_amdgcn_s_setprio(0);

            // ---- online softmax (log2), DPP reductions, defer-rescale ----
            const bool masked = (kt == qt);
            float p[4][4], tmax[4];
#pragma unroll
            for (int j = 0; j < 4; j++) {
                float v0 = -3e38f;
#pragma unroll
                for (int ni = 0; ni < 4; ni++) {
                    float sc = sacc[ni][j];
                    if (masked && (kb0 + ni * 16 + lr > qw0 + g * 4 + j)) sc = -3e38f;
                    p[ni][j] = sc;
                    v0 = fmaxf(v0, sc);
                }
                tmax[j] = v0;
            }
#pragma unroll
            for (int j = 0; j < 4; j++) tmax[j] = red16_max(tmax[j]);

            bool needb = false;
#pragma unroll
            for (int j = 0; j < 4; j++) needb = needb || (tmax[j] > m[j] + 7.f);
            const bool doresc = __any((int)needb);

            float cj[4], psum[4];
#pragma unroll
            for (int j = 0; j < 4; j++) {
                float mn = m[j];
                if (doresc) {
                    mn = fmaxf(m[j], tmax[j]);
                    cj[j] = __builtin_amdgcn_exp2f(m[j] - mn);
                    m[j] = mn;
                }
                float ps = 0.f;
#pragma unroll
                for (int ni = 0; ni < 4; ni++) {
                    const float e = __builtin_amdgcn_exp2f(p[ni][j] - mn);
                    p[ni][j] = e;
                    ps += e;
                }
                psum[j] = ps;
            }

            // ---- P -> bf16 via LDS transpose (overlaps the DPP sum) ----
#pragma unroll
            for (int ni = 0; ni < 4; ni++)
#pragma unroll
                for (int j = 0; j < 4; j++)
                    Pl[w][g * 4 + j][ni * 16 + lr] = (short)f2b(p[ni][j]);

#pragma unroll
            for (int j = 0; j < 4; j++) psum[j] = red16_sum(psum[j]);

            if (doresc) {
#pragma unroll
                for (int j = 0; j < 4; j++) lsum[j] = lsum[j] * cj[j] + psum[j];
#pragma unroll
                for (int di = 0; di < 8; di++)
#pragma unroll
                    for (int j = 0; j < 4; j++) oacc[di][j] *= cj[j];
            } else {
#pragma unroll
                for (int j = 0; j < 4; j++) lsum[j] += psum[j];
            }

            // ---- PV: O += P[16x64] @ V[64x128] ----
            __builtin_amdgcn_s_setprio(1);
#pragma unroll
            for (int kk = 0; kk < 2; kk++) {
                const s8v pa = *(const s8v*)&Pl[w][lr][kk * 32 + g * 8];
#pragma unroll
                for (int di = 0; di < 8; di++) {
                    const int r = di * 16 + lr;
                    const int ph = (kk * 4 + g) ^ (r & 7);
                    const s8v vb = *(const s8v*)&Vs[r][ph * 8];
                    oacc[di] = MFMA(pa, vb, oacc[di]);
                }
            }
            __builtin_amdgcn_s_setprio(0);
            __syncthreads();                         // reads done before next stage
        }

        // ---- epilogue: 1/l, sigmoid gate, store into qkv q-columns ----
        float linv[4];
#pragma unroll
        for (int j = 0; j < 4; j++) linv[j] = 1.f / lsum[j];
#pragma unroll
        for (int di = 0; di < 8; di++) {
            const int d = di * 16 + lr;
#pragma unroll
            for (int j = 0; j < 4; j++) {
                const int q = qw0 + g * 4 + j;
                const size_t base = (size_t)(b * S_ + q) * NQKV + h * 256;
                const float gate = b2f(qkv[base + 128 + d]);
                const float o = oacc[di][j] * linv[j] * (1.f / (1.f + __expf(-gate)));
                qkv[base + d] = (short)f2b(o);
            }
        }
    }
}

// ---------------------------------------------------------------------------
extern "C" void kernel_launch(void* const* d_in, const int* in_sizes, int n_in,
                              void* d_out, int out_size, void* d_ws, size_t ws_size,
                              hipStream_t stream) {
    const float* hs = (const float*)d_in[0];
    const float* cosb = (const float*)d_in[1];
    const float* sinb = (const float*)d_in[2];
    const float* Wq = (const float*)d_in[3];
    const float* Wk = (const float*)d_in[4];
    const float* Wv = (const float*)d_in[5];
    const float* Wo = (const float*)d_in[6];
    const float* qnw = (const float*)d_in[7];
    const float* knw = (const float*)d_in[8];
    float* out = (float*)d_out;

    short* ws = (short*)d_ws;
    short* Wot = ws;                  // 4194304
    short* Wt  = ws + 4194304;        // 12582912 (Wq^T rows 0..4095, Wk^T 4096.., Wv^T 5120..)
    short* hsb = ws + 16777216;       // 8388608
    short* qkv = ws + 25165824;       // 25165824  (total = 50331648 shorts = 96 MiB)
    // reuse after QKV gemm:
    short* qro = Wt;                  // 8388608
    short* kro = Wt + 8388608;        // 4194304
    short* vtb = hsb;                 // 4194304

    const int M = B_ * S_;

    // fused prep: hs->bf16 + all weight transposes, one launch
    prep_all<<<24576, 256, 0, stream>>>(hs, Wq, Wk, Wv, Wo, hsb, Wt, Wot);

    // merged QKV projection: 256^2 3-buffer deep-pipelined MFMA GEMM
    gemm256<<<dim3(24, 16), 512, 0, stream>>>(hsb, Wt, qkv, M, NQKV, HID_);

    // fused RMSNorm+RoPE (2 rows/block) + V transpose, one launch
    norm_vtrans<<<6144, 256, 0, stream>>>((const bf16*)qkv, qnw, knw, cosb, sinb,
                                          (bf16*)qro, (bf16*)kro, vtb);

    // causal GQA attention + gate (writes into qkv q-columns), paired q-tiles
    flash_mfma<<<dim3(16, 32), 256, 0, stream>>>(qro, kro, vtb, qkv);

    // output projection (fp32 out): 256x128-tile 3-buffer pipeline, 1 blk/CU
    gemm_wo<<<dim3(16, 16), 512, 0, stream>>>(qkv, Wot, out, M, HID_, 2048);
}